// Round 5
// baseline (378.630 us; speedup 1.0000x reference)
//
#include <hip/hip_runtime.h>
#include <math.h>

#define NN 100000      // nodes
#define DD 64          // dim
#define NE 1200000     // edges (without self-loops)
#define NB 391         // buckets of 256 nodes (= ceil(NN/256))
#define SCH 2048       // edges per scatter block

__device__ __forceinline__ float wave_sum64(float v) {
    #pragma unroll
    for (int o = 1; o < 64; o <<= 1) v += __shfl_xor(v, o, 64);
    return v;
}

__device__ __forceinline__ float gelu_exact(float x) {
    return 0.5f * x * (1.0f + erff(x * 0.70710678118654752f));
}

__device__ __forceinline__ float leaky(float x) {
    return fmaxf(x, 0.f) + 0.2f * fminf(x, 0.f);
}

// ---------------- CSR build: two-level bucket sort ----------------

__global__ __launch_bounds__(256) void k_bcount(const int* __restrict__ tgt, int* __restrict__ bcnt) {
    __shared__ int h[NB];
    for (int i = threadIdx.x; i < NB; i += 256) h[i] = 0;
    __syncthreads();
    const int stride = gridDim.x * 256;
    for (int i = blockIdx.x * 256 + threadIdx.x; i < NE; i += stride)
        atomicAdd(&h[tgt[i] >> 8], 1);
    __syncthreads();
    for (int i = threadIdx.x; i < NB; i += 256)
        if (h[i]) atomicAdd(&bcnt[i], h[i]);
}

__global__ __launch_bounds__(512) void k_bscan(const int* __restrict__ bcnt,
                                               int* __restrict__ bbase, int* __restrict__ wbase) {
    __shared__ int s[512];
    const int tid = threadIdx.x;
    const int v = (tid < NB) ? bcnt[tid] : 0;
    s[tid] = v;
    __syncthreads();
    for (int o = 1; o < 512; o <<= 1) {
        int t = (tid >= o) ? s[tid - o] : 0;
        __syncthreads();
        s[tid] += t;
        __syncthreads();
    }
    if (tid < NB) {
        int ex = s[tid] - v;
        bbase[tid] = ex;
        wbase[tid] = ex;
    }
    if (tid == NB - 1) bbase[NB] = s[tid];   // = NE
}

__global__ __launch_bounds__(256) void k_bscatter(const int* __restrict__ src, const int* __restrict__ tgt,
                                                  int* __restrict__ wbase, unsigned int* __restrict__ ebuf) {
    __shared__ int stgt[SCH];
    __shared__ unsigned short srk[SCH];
    __shared__ int hist[NB];
    __shared__ int hbase[NB];
    const int base = blockIdx.x * SCH;
    const int cnt = min(SCH, NE - base);
    const int tid = threadIdx.x;
    for (int i = tid; i < NB; i += 256) hist[i] = 0;
    for (int i = tid; i < cnt; i += 256) stgt[i] = tgt[base + i];
    __syncthreads();
    for (int i = tid; i < cnt; i += 256)
        srk[i] = (unsigned short)atomicAdd(&hist[stgt[i] >> 8], 1);
    __syncthreads();
    for (int b = tid; b < NB; b += 256) {
        int c = hist[b];
        hbase[b] = c ? atomicAdd(&wbase[b], c) : 0;
    }
    __syncthreads();
    for (int i = tid; i < cnt; i += 256) {
        int t = stgt[i];
        unsigned int e = ((unsigned int)src[base + i] << 8) | (unsigned int)(t & 255);
        ebuf[hbase[t >> 8] + (int)srk[i]] = e;
    }
}

__global__ __launch_bounds__(256) void k_bfinal(const int* __restrict__ bbase,
                                                const unsigned int* __restrict__ ebuf,
                                                int* __restrict__ rowptr, int* __restrict__ csr) {
    __shared__ int hist[256];
    __shared__ int pos[256];
    __shared__ int wsum[4];
    const int b = blockIdx.x, tid = threadIdx.x;
    const int bb = bbase[b], be = bbase[b + 1];
    hist[tid] = 0;
    __syncthreads();
    for (int i = bb + tid; i < be; i += 256) atomicAdd(&hist[ebuf[i] & 255u], 1);
    __syncthreads();
    const int v = hist[tid];
    const int lane = tid & 63, w = tid >> 6;
    int sc = v;
    #pragma unroll
    for (int o = 1; o < 64; o <<= 1) { int t = __shfl_up(sc, o, 64); if (lane >= o) sc += t; }
    if (lane == 63) wsum[w] = sc;
    __syncthreads();
    int off = 0;
    for (int k = 0; k < w; ++k) off += wsum[k];
    const int rp = bb + off + sc - v;
    const int node = b * 256 + tid;
    if (node <= NN) rowptr[node] = rp;
    pos[tid] = rp;
    __syncthreads();
    for (int i = bb + tid; i < be; i += 256) {
        unsigned int e = ebuf[i];
        int p = atomicAdd(&pos[e & 255u], 1);
        csr[p] = (int)(e >> 8);
    }
}

// ---------------- node prep: LayerNorm + xl = y@Wl, xr = y@Wr ----------------
// W columns live in registers (each lane owns column `lane` of Wl and Wr).
__global__ __launch_bounds__(256, 2) void k_prep(
    const float* __restrict__ h,
    const float* __restrict__ gamma, const float* __restrict__ beta,
    const float* __restrict__ Wl, const float* __restrict__ Wr,
    float* __restrict__ xl, float* __restrict__ xr)
{
    __shared__ float sy[4 * DD];
    const int lane  = threadIdx.x & 63;
    const int wslot = threadIdx.x >> 6;
    const int wid   = (blockIdx.x * 256 + threadIdx.x) >> 6;
    const int nw    = gridDim.x * 4;
    float wl[DD], wr[DD];
    #pragma unroll
    for (int k = 0; k < DD; ++k) {
        wl[k] = Wl[k * DD + lane];
        wr[k] = Wr[k * DD + lane];
    }
    const float g = gamma[lane], b = beta[lane];
    for (int n = wid; n < NN; n += nw) {
        float v    = h[n * DD + lane];
        float mean = wave_sum64(v) * 0.015625f;
        float d    = v - mean;
        float var  = wave_sum64(d * d) * 0.015625f;
        float y    = d * rsqrtf(var + 1e-5f) * g + b;
        sy[wslot * DD + lane] = y;
        float al = 0.f, ar = 0.f;
        #pragma unroll
        for (int k4 = 0; k4 < 16; ++k4) {
            float4 yv = *(const float4*)&sy[wslot * DD + k4 * 4];
            al = fmaf(yv.x, wl[k4 * 4 + 0], al);
            ar = fmaf(yv.x, wr[k4 * 4 + 0], ar);
            al = fmaf(yv.y, wl[k4 * 4 + 1], al);
            ar = fmaf(yv.y, wr[k4 * 4 + 1], ar);
            al = fmaf(yv.z, wl[k4 * 4 + 2], al);
            ar = fmaf(yv.z, wr[k4 * 4 + 2], ar);
            al = fmaf(yv.w, wl[k4 * 4 + 3], al);
            ar = fmaf(yv.w, wr[k4 * 4 + 3], ar);
        }
        xl[n * DD + lane] = al;
        xr[n * DD + lane] = ar;
    }
}

// ---------------- aggregation: one wave per target node, 16 lanes x 4 edges ----------------
// FUSE_POST: apply out = gelu(...)+h_in then project with post_w/post_b instead of storing h.
template<bool FUSE_POST>
__global__ __launch_bounds__(256, 4) void k_agg_t(
    const int* __restrict__ rowptr, const int* __restrict__ csr,
    const float* __restrict__ xl, const float* __restrict__ xr,
    const float* __restrict__ att, const float* __restrict__ cbias,
    const float* __restrict__ h_in, float* __restrict__ h_out,
    const float* __restrict__ pw, const float* __restrict__ pb)
{
    __shared__ float4 sh2[4][16];
    const int lane = threadIdx.x & 63;
    const int li   = lane & 15;     // feature-quad index
    const int sub  = lane >> 4;     // edge slot 0..3
    const int wslot = threadIdx.x >> 6;
    const int wid  = (blockIdx.x * 256 + threadIdx.x) >> 6;
    const int nw   = gridDim.x * 4;
    const float4 a4  = *(const float4*)&att[li * 4];
    const float4 cb4 = *(const float4*)&cbias[li * 4];
    float4 pwc[16];
    float4 pb4 = make_float4(0.f, 0.f, 0.f, 0.f);
    if (FUSE_POST) {
        #pragma unroll
        for (int j = 0; j < 16; ++j)
            pwc[j] = *(const float4*)&pw[(16 * sub + j) * DD + 4 * li];
        pb4 = *(const float4*)&pb[4 * li];
    }
    for (int n = wid; n < NN; n += nw) {
        const float4 xrt = *(const float4*)&xr[(size_t)n * DD + li * 4];
        const int beg = rowptr[n], end = rowptr[n + 1];
        // virtual edge list: j in [beg-1, end); j == beg-1 is the self-loop
        int j = beg - 1 + sub;
        bool val = j < end;
        float4 v = make_float4(0.f, 0.f, 0.f, 0.f);
        if (val) {
            int s = (j == beg - 1) ? n : csr[j];
            v = *(const float4*)&xl[(size_t)s * DD + li * 4];
        }
        float  den = 0.f;
        float4 acc = make_float4(0.f, 0.f, 0.f, 0.f);
        const int nch = (end - beg + 4) >> 2;   // ceil((len+1)/4)
        for (int c = 0; c < nch; ++c) {
            float4 cur = v;
            bool  cval = val;
            j += 4;
            val = j < end;
            v = make_float4(0.f, 0.f, 0.f, 0.f);
            if (val) {
                int s = csr[j];
                v = *(const float4*)&xl[(size_t)s * DD + li * 4];
            }
            float p = leaky(cur.x + xrt.x) * a4.x;
            p = fmaf(leaky(cur.y + xrt.y), a4.y, p);
            p = fmaf(leaky(cur.z + xrt.z), a4.z, p);
            p = fmaf(leaky(cur.w + xrt.w), a4.w, p);
            p += __shfl_xor(p, 1, 64);
            p += __shfl_xor(p, 2, 64);
            p += __shfl_xor(p, 4, 64);
            p += __shfl_xor(p, 8, 64);
            float ex = cval ? __expf(p) : 0.f;
            den += ex;
            acc.x = fmaf(ex, cur.x, acc.x);
            acc.y = fmaf(ex, cur.y, acc.y);
            acc.z = fmaf(ex, cur.z, acc.z);
            acc.w = fmaf(ex, cur.w, acc.w);
        }
        #pragma unroll
        for (int o = 16; o < 64; o <<= 1) {
            acc.x += __shfl_xor(acc.x, o, 64);
            acc.y += __shfl_xor(acc.y, o, 64);
            acc.z += __shfl_xor(acc.z, o, 64);
            acc.w += __shfl_xor(acc.w, o, 64);
            den   += __shfl_xor(den,   o, 64);
        }
        if (!FUSE_POST) {
            if (sub == 0) {
                const float id = 1.f / (den + 1e-16f);
                const float4 hi = *(const float4*)&h_in[(size_t)n * DD + li * 4];
                float4 o4;
                o4.x = gelu_exact(fmaf(acc.x, id, cb4.x)) + hi.x;
                o4.y = gelu_exact(fmaf(acc.y, id, cb4.y)) + hi.y;
                o4.z = gelu_exact(fmaf(acc.z, id, cb4.z)) + hi.z;
                o4.w = gelu_exact(fmaf(acc.w, id, cb4.w)) + hi.w;
                *(float4*)&h_out[(size_t)n * DD + li * 4] = o4;
            }
        } else {
            if (sub == 0) {
                const float id = 1.f / (den + 1e-16f);
                const float4 hi = *(const float4*)&h_in[(size_t)n * DD + li * 4];
                float4 o4;
                o4.x = gelu_exact(fmaf(acc.x, id, cb4.x)) + hi.x;
                o4.y = gelu_exact(fmaf(acc.y, id, cb4.y)) + hi.y;
                o4.z = gelu_exact(fmaf(acc.z, id, cb4.z)) + hi.z;
                o4.w = gelu_exact(fmaf(acc.w, id, cb4.w)) + hi.w;
                sh2[wslot][li] = o4;      // publish h2 quad to the wave
            }
            // same-wave LDS write->read; compiler inserts the lgkmcnt wait
            float4 p4 = make_float4(0.f, 0.f, 0.f, 0.f);
            #pragma unroll
            for (int jq = 0; jq < 4; ++jq) {
                float4 hq = sh2[wslot][sub * 4 + jq];
                p4.x = fmaf(hq.x, pwc[4 * jq + 0].x, p4.x);
                p4.y = fmaf(hq.x, pwc[4 * jq + 0].y, p4.y);
                p4.z = fmaf(hq.x, pwc[4 * jq + 0].z, p4.z);
                p4.w = fmaf(hq.x, pwc[4 * jq + 0].w, p4.w);
                p4.x = fmaf(hq.y, pwc[4 * jq + 1].x, p4.x);
                p4.y = fmaf(hq.y, pwc[4 * jq + 1].y, p4.y);
                p4.z = fmaf(hq.y, pwc[4 * jq + 1].z, p4.z);
                p4.w = fmaf(hq.y, pwc[4 * jq + 1].w, p4.w);
                p4.x = fmaf(hq.z, pwc[4 * jq + 2].x, p4.x);
                p4.y = fmaf(hq.z, pwc[4 * jq + 2].y, p4.y);
                p4.z = fmaf(hq.z, pwc[4 * jq + 2].z, p4.z);
                p4.w = fmaf(hq.z, pwc[4 * jq + 2].w, p4.w);
                p4.x = fmaf(hq.w, pwc[4 * jq + 3].x, p4.x);
                p4.y = fmaf(hq.w, pwc[4 * jq + 3].y, p4.y);
                p4.z = fmaf(hq.w, pwc[4 * jq + 3].z, p4.z);
                p4.w = fmaf(hq.w, pwc[4 * jq + 3].w, p4.w);
            }
            #pragma unroll
            for (int o = 16; o < 64; o <<= 1) {
                p4.x += __shfl_xor(p4.x, o, 64);
                p4.y += __shfl_xor(p4.y, o, 64);
                p4.z += __shfl_xor(p4.z, o, 64);
                p4.w += __shfl_xor(p4.w, o, 64);
            }
            if (sub == 0) {
                float4 o4;
                o4.x = p4.x + pb4.x;
                o4.y = p4.y + pb4.y;
                o4.z = p4.z + pb4.z;
                o4.w = p4.w + pb4.w;
                *(float4*)&h_out[(size_t)n * DD + li * 4] = o4;
            }
        }
    }
}

extern "C" void kernel_launch(void* const* d_in, const int* in_sizes, int n_in,
                              void* d_out, int out_size, void* d_ws, size_t ws_size,
                              hipStream_t stream) {
    const int*   edge_index = (const int*)d_in[1];
    const int*   src   = edge_index;
    const int*   tgt   = edge_index + NE;
    const float* emb   = (const float*)d_in[2];
    const float* ln_g  = (const float*)d_in[3];
    const float* ln_b  = (const float*)d_in[4];
    const float* Wl    = (const float*)d_in[5];
    const float* Wr    = (const float*)d_in[6];
    const float* att   = (const float*)d_in[7];
    const float* cbias = (const float*)d_in[8];
    const float* pw    = (const float*)d_in[9];
    const float* pb    = (const float*)d_in[10];
    float* out = (float*)d_out;

    float* xl = (float*)d_ws;
    float* xr = xl + (size_t)NN * DD;
    int* csr             = (int*)(xr + (size_t)NN * DD);
    unsigned int* ebuf   = (unsigned int*)(csr + NE);
    int* rowptr          = (int*)(ebuf + NE);       // NN+1 (+pad)
    int* bcnt            = rowptr + NN + 8;
    int* bbase           = bcnt + NB;               // NB+1
    int* wbase           = bbase + NB + 1;

    const int PREP_BLOCKS = 512;    // 2 blocks/CU at 8 waves/CU
    const int AGG_BLOCKS  = 1024;   // 4 blocks/CU at 16 waves/CU

    // ---- CSR build (two-level bucket sort by target) ----
    hipMemsetAsync(bcnt, 0, NB * sizeof(int), stream);
    k_bcount<<<256, 256, 0, stream>>>(tgt, bcnt);
    k_bscan<<<1, 512, 0, stream>>>(bcnt, bbase, wbase);
    k_bscatter<<<(NE + SCH - 1) / SCH, 256, 0, stream>>>(src, tgt, wbase, ebuf);
    k_bfinal<<<NB, 256, 0, stream>>>(bbase, ebuf, rowptr, csr);

    // ---- layer 0 ----
    k_prep<<<PREP_BLOCKS, 256, 0, stream>>>(emb, ln_g, ln_b, Wl, Wr, xl, xr);
    k_agg_t<false><<<AGG_BLOCKS, 256, 0, stream>>>(rowptr, csr, xl, xr, att, cbias,
                                                   emb, out, nullptr, nullptr);          // h1 -> out

    // ---- layer 1 (aggregation fused with final projection) ----
    k_prep<<<PREP_BLOCKS, 256, 0, stream>>>(out, ln_g + DD, ln_b + DD,
                                            Wl + DD * DD, Wr + DD * DD, xl, xr);
    k_agg_t<true><<<AGG_BLOCKS, 256, 0, stream>>>(rowptr, csr, xl, xr, att + DD, cbias + DD,
                                                  out, out, pw, pb);                     // final out
}

// Round 6
// 330.015 us; speedup vs baseline: 1.1473x; 1.1473x over previous
//
#include <hip/hip_runtime.h>
#include <math.h>

#define NN 100000      // nodes
#define DD 64          // dim
#define NE 1200000     // edges (without self-loops)
#define NB 391         // buckets of 256 nodes (= ceil(NN/256))
#define SCH 2048       // edges per scatter block

__device__ __forceinline__ float wave_sum64(float v) {
    #pragma unroll
    for (int o = 1; o < 64; o <<= 1) v += __shfl_xor(v, o, 64);
    return v;
}

__device__ __forceinline__ float gelu_exact(float x) {
    return 0.5f * x * (1.0f + erff(x * 0.70710678118654752f));
}

__device__ __forceinline__ float leaky(float x) {
    return fmaxf(x, 0.f) + 0.2f * fminf(x, 0.f);
}

// ---------------- CSR build: two-level bucket sort (self-loops embedded) ----------------

__global__ __launch_bounds__(256) void k_bcount(const int* __restrict__ tgt, int* __restrict__ bcnt) {
    __shared__ int h[NB];
    for (int i = threadIdx.x; i < NB; i += 256) h[i] = 0;
    __syncthreads();
    const int stride = gridDim.x * 256;
    for (int i = blockIdx.x * 256 + threadIdx.x; i < NE; i += stride)
        atomicAdd(&h[tgt[i] >> 8], 1);
    __syncthreads();
    for (int i = threadIdx.x; i < NB; i += 256)
        if (h[i]) atomicAdd(&bcnt[i], h[i]);
}

__global__ __launch_bounds__(512) void k_bscan(const int* __restrict__ bcnt,
                                               int* __restrict__ bbase, int* __restrict__ wbase) {
    __shared__ int s[512];
    const int tid = threadIdx.x;
    const int v = (tid < NB) ? bcnt[tid] : 0;
    s[tid] = v;
    __syncthreads();
    for (int o = 1; o < 512; o <<= 1) {
        int t = (tid >= o) ? s[tid - o] : 0;
        __syncthreads();
        s[tid] += t;
        __syncthreads();
    }
    if (tid < NB) {
        int ex = s[tid] - v;
        bbase[tid] = ex;
        wbase[tid] = ex;
    }
    if (tid == NB - 1) bbase[NB] = s[tid];   // = NE
}

__global__ __launch_bounds__(256) void k_bscatter(const int* __restrict__ src, const int* __restrict__ tgt,
                                                  int* __restrict__ wbase, unsigned int* __restrict__ ebuf) {
    __shared__ int stgt[SCH];
    __shared__ unsigned short srk[SCH];
    __shared__ int hist[NB];
    __shared__ int hbase[NB];
    const int base = blockIdx.x * SCH;
    const int cnt = min(SCH, NE - base);
    const int tid = threadIdx.x;
    for (int i = tid; i < NB; i += 256) hist[i] = 0;
    for (int i = tid; i < cnt; i += 256) stgt[i] = tgt[base + i];
    __syncthreads();
    for (int i = tid; i < cnt; i += 256)
        srk[i] = (unsigned short)atomicAdd(&hist[stgt[i] >> 8], 1);
    __syncthreads();
    for (int b = tid; b < NB; b += 256) {
        int c = hist[b];
        hbase[b] = c ? atomicAdd(&wbase[b], c) : 0;
    }
    __syncthreads();
    for (int i = tid; i < cnt; i += 256) {
        int t = stgt[i];
        unsigned int e = ((unsigned int)src[base + i] << 8) | (unsigned int)(t & 255);
        ebuf[hbase[t >> 8] + (int)srk[i]] = e;
    }
}

// one block per bucket: histogram -> rowptr (shifted +node for self-slot) -> self + edges
__global__ __launch_bounds__(256) void k_bfinal(const int* __restrict__ bbase,
                                                const unsigned int* __restrict__ ebuf,
                                                int* __restrict__ rowptr, int* __restrict__ csr) {
    __shared__ int hist[256];
    __shared__ int pos[256];
    __shared__ int wsum[4];
    const int b = blockIdx.x, tid = threadIdx.x;
    const int bb = bbase[b], be = bbase[b + 1];
    hist[tid] = 0;
    __syncthreads();
    for (int i = bb + tid; i < be; i += 256) atomicAdd(&hist[ebuf[i] & 255u], 1);
    __syncthreads();
    const int v = hist[tid];
    const int lane = tid & 63, w = tid >> 6;
    int sc = v;
    #pragma unroll
    for (int o = 1; o < 64; o <<= 1) { int t = __shfl_up(sc, o, 64); if (lane >= o) sc += t; }
    if (lane == 63) wsum[w] = sc;
    __syncthreads();
    int off = 0;
    for (int k = 0; k < w; ++k) off += wsum[k];
    const int node = b * 256 + tid;
    const int rp = bb + off + sc - v + node;     // +node: one self slot per preceding node
    if (node < NN) {
        rowptr[node] = rp;
        csr[rp] = node;                          // self-loop first
    } else if (node == NN) {
        rowptr[NN] = rp;                         // = NE + NN
    }
    pos[tid] = rp + 1;                           // edges start after self
    __syncthreads();
    for (int i = bb + tid; i < be; i += 256) {
        unsigned int e = ebuf[i];
        int p = atomicAdd(&pos[e & 255u], 1);
        csr[p] = (int)(e >> 8);
    }
}

// ---------------- node prep: LN folded into weights; scalar-load h row ----------------
// wave pair per node set: even wave -> xl (Wl), odd wave -> xr (Wr).
// xo[c] = rho*(dot - mean*S) + C, dot = sum_k h_k*(g_k*W[k][c]), S = sum_k g_k*W[k][c], C = sum_k b_k*W[k][c]
__global__ __launch_bounds__(256) void k_prep(
    const float* __restrict__ h,
    const float* __restrict__ gamma, const float* __restrict__ beta,
    const float* __restrict__ Wl, const float* __restrict__ Wr,
    float* __restrict__ xl, float* __restrict__ xr)
{
    const int lane = threadIdx.x & 63;
    const int wid  = (blockIdx.x * 256 + threadIdx.x) >> 6;
    const int half = wid & 1;
    const int nw   = (gridDim.x * 4) >> 1;
    const float* __restrict__ W = half ? Wr : Wl;
    float* __restrict__ xo      = half ? xr : xl;
    float A[DD];
    float S = 0.f, C = 0.f;
    #pragma unroll
    for (int k = 0; k < DD; ++k) {
        float wv = W[k * DD + lane];
        float gk = gamma[k];
        float bk = beta[k];
        A[k] = wv * gk;
        S += A[k];
        C = fmaf(bk, wv, C);
    }
    for (int n = (wid >> 1); n < NN; n += nw) {
        const int nu = __builtin_amdgcn_readfirstlane(n);
        const float* __restrict__ hr = h + (size_t)nu * DD;
        float hv   = h[(size_t)n * DD + lane];
        float mean = wave_sum64(hv) * 0.015625f;
        float d    = hv - mean;
        float var  = wave_sum64(d * d) * 0.015625f;
        float rho  = rsqrtf(var + 1e-5f);
        float dot = 0.f;
        #pragma unroll
        for (int k = 0; k < DD; ++k) dot = fmaf(hr[k], A[k], dot);
        float t = fmaf(-mean, S, dot);
        xo[(size_t)n * DD + lane] = fmaf(rho, t, C);
    }
}

// ---------------- aggregation: one wave per target node, 16 lanes x 4 edges ----------------
__global__ __launch_bounds__(256) void k_agg(
    const int* __restrict__ rowptr, const int* __restrict__ csr,
    const float* __restrict__ xl, const float* __restrict__ xr,
    const float* __restrict__ att, const float* __restrict__ cbias,
    const float* __restrict__ h_in, float* __restrict__ h_out)
{
    const int lane = threadIdx.x & 63;
    const int li   = lane & 15;     // feature-quad index
    const int sub  = lane >> 4;     // edge slot 0..3
    const int wid  = (blockIdx.x * 256 + threadIdx.x) >> 6;
    const int nw   = gridDim.x * 4;
    const float4 a4  = *(const float4*)&att[li * 4];
    const float4 cb4 = *(const float4*)&cbias[li * 4];
    for (int n = wid; n < NN; n += nw) {
        const float4 xrt = *(const float4*)&xr[(size_t)n * DD + li * 4];
        const int beg = rowptr[n], end = rowptr[n + 1];   // len >= 1 (self first)
        const int end1 = end - 1;
        int j  = beg + sub;
        int jc = min(j, end1);
        int s  = csr[jc];
        float4 v = *(const float4*)&xl[(size_t)s * DD + li * 4];
        float  den = 0.f;
        float4 acc = make_float4(0.f, 0.f, 0.f, 0.f);
        const int nch = (end - beg + 3) >> 2;
        for (int c = 0; c < nch; ++c) {
            float4 cur = v;
            const int jcur = j;
            j += 4;
            jc = min(j, end1);
            s  = csr[jc];
            v  = *(const float4*)&xl[(size_t)s * DD + li * 4];   // unconditional prefetch
            float p = leaky(cur.x + xrt.x) * a4.x;
            p = fmaf(leaky(cur.y + xrt.y), a4.y, p);
            p = fmaf(leaky(cur.z + xrt.z), a4.z, p);
            p = fmaf(leaky(cur.w + xrt.w), a4.w, p);
            p += __shfl_xor(p, 1, 64);
            p += __shfl_xor(p, 2, 64);
            p += __shfl_xor(p, 4, 64);
            p += __shfl_xor(p, 8, 64);
            float ex = (jcur < end) ? __expf(p) : 0.f;
            den += ex;
            acc.x = fmaf(ex, cur.x, acc.x);
            acc.y = fmaf(ex, cur.y, acc.y);
            acc.z = fmaf(ex, cur.z, acc.z);
            acc.w = fmaf(ex, cur.w, acc.w);
        }
        #pragma unroll
        for (int o = 16; o < 64; o <<= 1) {
            acc.x += __shfl_xor(acc.x, o, 64);
            acc.y += __shfl_xor(acc.y, o, 64);
            acc.z += __shfl_xor(acc.z, o, 64);
            acc.w += __shfl_xor(acc.w, o, 64);
            den   += __shfl_xor(den,   o, 64);
        }
        if (sub == 0) {
            const float id = 1.f / (den + 1e-16f);
            const float4 hi = *(const float4*)&h_in[(size_t)n * DD + li * 4];
            float4 o4;
            o4.x = gelu_exact(fmaf(acc.x, id, cb4.x)) + hi.x;
            o4.y = gelu_exact(fmaf(acc.y, id, cb4.y)) + hi.y;
            o4.z = gelu_exact(fmaf(acc.z, id, cb4.z)) + hi.z;
            o4.w = gelu_exact(fmaf(acc.w, id, cb4.w)) + hi.w;
            *(float4*)&h_out[(size_t)n * DD + li * 4] = o4;
        }
    }
}

// ---------------- final projection: out = h @ post_w + post_b (scalar-load h row) ----------------
__global__ __launch_bounds__(256) void k_final(
    const float* __restrict__ h,
    const float* __restrict__ pw, const float* __restrict__ pb,
    float* __restrict__ out)
{
    const int lane = threadIdx.x & 63;
    const int wid  = (blockIdx.x * 256 + threadIdx.x) >> 6;
    const int nw   = gridDim.x * 4;
    float w[DD];
    #pragma unroll
    for (int k = 0; k < DD; ++k) w[k] = pw[k * DD + lane];
    const float pbl = pb[lane];
    for (int n = wid; n < NN; n += nw) {
        const int nu = __builtin_amdgcn_readfirstlane(n);
        const float* __restrict__ hr = h + (size_t)nu * DD;
        float o = pbl;
        #pragma unroll
        for (int k = 0; k < DD; ++k) o = fmaf(hr[k], w[k], o);
        out[(size_t)n * DD + lane] = o;   // in-place safe: wave reads row n fully before store
    }
}

extern "C" void kernel_launch(void* const* d_in, const int* in_sizes, int n_in,
                              void* d_out, int out_size, void* d_ws, size_t ws_size,
                              hipStream_t stream) {
    const int*   edge_index = (const int*)d_in[1];
    const int*   src   = edge_index;
    const int*   tgt   = edge_index + NE;
    const float* emb   = (const float*)d_in[2];
    const float* ln_g  = (const float*)d_in[3];
    const float* ln_b  = (const float*)d_in[4];
    const float* Wl    = (const float*)d_in[5];
    const float* Wr    = (const float*)d_in[6];
    const float* att   = (const float*)d_in[7];
    const float* cbias = (const float*)d_in[8];
    const float* pw    = (const float*)d_in[9];
    const float* pb    = (const float*)d_in[10];
    float* out = (float*)d_out;

    float* xl = (float*)d_ws;
    float* xr = xl + (size_t)NN * DD;
    int* csr             = (int*)(xr + (size_t)NN * DD);   // NE + NN entries
    unsigned int* ebuf   = (unsigned int*)(csr + NE + NN);
    int* rowptr          = (int*)(ebuf + NE);              // NN+1 (+pad)
    int* bcnt            = rowptr + NN + 8;
    int* bbase           = bcnt + NB;                      // NB+1
    int* wbase           = bbase + NB + 1;

    const int PREP_BLOCKS  = 1024;   // 4096 waves (2048 wave-pairs), ~85 VGPR -> 16 waves/CU
    const int AGG_BLOCKS   = 2048;   // 8192 waves, VGPR<=64 -> up to 32 waves/CU
    const int FINAL_BLOCKS = 1024;

    // ---- CSR build (two-level bucket sort by target, self-loops embedded) ----
    hipMemsetAsync(bcnt, 0, NB * sizeof(int), stream);
    k_bcount<<<256, 256, 0, stream>>>(tgt, bcnt);
    k_bscan<<<1, 512, 0, stream>>>(bcnt, bbase, wbase);
    k_bscatter<<<(NE + SCH - 1) / SCH, 256, 0, stream>>>(src, tgt, wbase, ebuf);
    k_bfinal<<<NB, 256, 0, stream>>>(bbase, ebuf, rowptr, csr);

    // ---- layer 0 ----
    k_prep<<<PREP_BLOCKS, 256, 0, stream>>>(emb, ln_g, ln_b, Wl, Wr, xl, xr);
    k_agg<<<AGG_BLOCKS, 256, 0, stream>>>(rowptr, csr, xl, xr, att, cbias, emb, out);        // h1

    // ---- layer 1 ----
    k_prep<<<PREP_BLOCKS, 256, 0, stream>>>(out, ln_g + DD, ln_b + DD,
                                            Wl + DD * DD, Wr + DD * DD, xl, xr);
    k_agg<<<AGG_BLOCKS, 256, 0, stream>>>(rowptr, csr, xl, xr, att + DD, cbias + DD, out, out); // h2

    // ---- final projection ----
    k_final<<<FINAL_BLOCKS, 256, 0, stream>>>(out, pw, pb, out);
}

// Round 7
// 266.927 us; speedup vs baseline: 1.4185x; 1.2363x over previous
//
#include <hip/hip_runtime.h>
#include <math.h>

#define NN 100000      // nodes
#define DD 64          // dim
#define NE 1200000     // edges (without self-loops)
#define NB 391         // buckets of 256 nodes
#define SCH 2048       // edges per scatter block
#define GB ((NN + 63) / 64)   // 1563 row tiles for GEMM
#define HS 88          // LDS row stride in shorts (176B: 16B-aligned, <=2-way banks)

typedef __attribute__((ext_vector_type(8))) short bf16x8;
typedef __attribute__((ext_vector_type(4))) float f32x4;

__device__ __forceinline__ unsigned short f2bf(float x) {
    unsigned u = __float_as_uint(x);
    return (unsigned short)((u + 0x7FFFu + ((u >> 16) & 1u)) >> 16);   // RNE
}
__device__ __forceinline__ float bf2f(unsigned short b) {
    return __uint_as_float(((unsigned)b) << 16);
}

__device__ __forceinline__ float gelu_exact(float x) {
    return 0.5f * x * (1.0f + erff(x * 0.70710678118654752f));
}

__device__ __forceinline__ float leaky(float x) {
    return fmaxf(x, 0.f) + 0.2f * fminf(x, 0.f);
}

// ---------------- CSR build: two-level bucket sort (self-loops embedded) ----------------

__global__ __launch_bounds__(256) void k_bcount(const int* __restrict__ tgt, int* __restrict__ bcnt) {
    __shared__ int h[NB];
    for (int i = threadIdx.x; i < NB; i += 256) h[i] = 0;
    __syncthreads();
    const int stride = gridDim.x * 256;
    for (int i = blockIdx.x * 256 + threadIdx.x; i < NE; i += stride)
        atomicAdd(&h[tgt[i] >> 8], 1);
    __syncthreads();
    for (int i = threadIdx.x; i < NB; i += 256)
        if (h[i]) atomicAdd(&bcnt[i], h[i]);
}

__global__ __launch_bounds__(512) void k_bscan(const int* __restrict__ bcnt,
                                               int* __restrict__ bbase, int* __restrict__ wbase) {
    __shared__ int s[512];
    const int tid = threadIdx.x;
    const int v = (tid < NB) ? bcnt[tid] : 0;
    s[tid] = v;
    __syncthreads();
    for (int o = 1; o < 512; o <<= 1) {
        int t = (tid >= o) ? s[tid - o] : 0;
        __syncthreads();
        s[tid] += t;
        __syncthreads();
    }
    if (tid < NB) {
        int ex = s[tid] - v;
        bbase[tid] = ex;
        wbase[tid] = ex;
    }
    if (tid == NB - 1) bbase[NB] = s[tid];   // = NE
}

__global__ __launch_bounds__(256) void k_bscatter(const int* __restrict__ src, const int* __restrict__ tgt,
                                                  int* __restrict__ wbase, unsigned int* __restrict__ ebuf) {
    __shared__ int stgt[SCH];
    __shared__ unsigned short srk[SCH];
    __shared__ int hist[NB];
    __shared__ int hbase[NB];
    const int base = blockIdx.x * SCH;
    const int cnt = min(SCH, NE - base);
    const int tid = threadIdx.x;
    for (int i = tid; i < NB; i += 256) hist[i] = 0;
    for (int i = tid; i < cnt; i += 256) stgt[i] = tgt[base + i];
    __syncthreads();
    for (int i = tid; i < cnt; i += 256)
        srk[i] = (unsigned short)atomicAdd(&hist[stgt[i] >> 8], 1);
    __syncthreads();
    for (int b = tid; b < NB; b += 256) {
        int c = hist[b];
        hbase[b] = c ? atomicAdd(&wbase[b], c) : 0;
    }
    __syncthreads();
    for (int i = tid; i < cnt; i += 256) {
        int t = stgt[i];
        unsigned int e = ((unsigned int)src[base + i] << 8) | (unsigned int)(t & 255);
        ebuf[hbase[t >> 8] + (int)srk[i]] = e;
    }
}

__global__ __launch_bounds__(256) void k_bfinal(const int* __restrict__ bbase,
                                                const unsigned int* __restrict__ ebuf,
                                                int* __restrict__ rowptr, int* __restrict__ csr) {
    __shared__ int hist[256];
    __shared__ int pos[256];
    __shared__ int wsum[4];
    const int b = blockIdx.x, tid = threadIdx.x;
    const int bb = bbase[b], be = bbase[b + 1];
    hist[tid] = 0;
    __syncthreads();
    for (int i = bb + tid; i < be; i += 256) atomicAdd(&hist[ebuf[i] & 255u], 1);
    __syncthreads();
    const int v = hist[tid];
    const int lane = tid & 63, w = tid >> 6;
    int sc = v;
    #pragma unroll
    for (int o = 1; o < 64; o <<= 1) { int t = __shfl_up(sc, o, 64); if (lane >= o) sc += t; }
    if (lane == 63) wsum[w] = sc;
    __syncthreads();
    int off = 0;
    for (int k = 0; k < w; ++k) off += wsum[k];
    const int node = b * 256 + tid;
    const int rp = bb + off + sc - v + node;     // +node: one self slot per preceding node
    if (node < NN) {
        rowptr[node] = rp;
        csr[rp] = node;                          // self-loop first
    } else if (node == NN) {
        rowptr[NN] = rp;                         // = NE + NN
    }
    pos[tid] = rp + 1;                           // edges start after self
    __syncthreads();
    for (int i = bb + tid; i < be; i += 256) {
        unsigned int e = ebuf[i];
        int p = atomicAdd(&pos[e & 255u], 1);
        csr[p] = (int)(e >> 8);
    }
}

// ---------------- weight precompute: A = diag(g)W (bf16 hi/lo), S = g@W, C = beta@W ----------------
// aT layout: hi block [128][64] then lo block [128][64] (c-major, k contiguous).
__global__ __launch_bounds__(128) void k_wprep(
    const float* __restrict__ Wl, const float* __restrict__ Wr,
    const float* __restrict__ g, const float* __restrict__ be,
    unsigned short* __restrict__ aT, float* __restrict__ S, float* __restrict__ C)
{
    const int c = threadIdx.x;          // 0..127
    const float* W = (c < 64) ? Wl : Wr;
    const int cc = c & 63;
    float s = 0.f, cC = 0.f;
    unsigned short* hi_p = aT + c * 64;
    unsigned short* lo_p = aT + 128 * 64 + c * 64;
    #pragma unroll 8
    for (int k = 0; k < 64; ++k) {
        float w = W[k * 64 + cc];
        float a = g[k] * w;
        unsigned short hi = f2bf(a);
        unsigned short lo = f2bf(a - bf2f(hi));
        hi_p[k] = hi; lo_p[k] = lo;
        s += a;
        cC = fmaf(be[k], w, cC);
    }
    S[c] = s; C[c] = cC;
}

__global__ __launch_bounds__(64) void k_wfinal(
    const float* __restrict__ pw, const float* __restrict__ pb,
    unsigned short* __restrict__ fT, float* __restrict__ Cf)
{
    const int c = threadIdx.x;  // 0..63
    unsigned short* hi_p = fT + c * 64;
    unsigned short* lo_p = fT + 64 * 64 + c * 64;
    #pragma unroll 8
    for (int k = 0; k < 64; ++k) {
        float w = pw[k * 64 + c];
        unsigned short hi = f2bf(w);
        unsigned short lo = f2bf(w - bf2f(hi));
        hi_p[k] = hi; lo_p[k] = lo;
    }
    Cf[c] = pb[c];
}

// ---------------- MFMA node GEMM: [64-node tile] x [64 k] @ [64 k x NCT*16 cols] ----------------
// LN=true: out = rho*(h@A) - rho*mean*S + C, split across xl (cols<64) / xr (cols>=64).
// LN=false: out = h@A + C -> outp (in-place safe per 64-row tile).
template<int CTW, bool LN>
__global__ __launch_bounds__(256) void k_gemm(
    const float* __restrict__ h, const unsigned short* __restrict__ aT,
    const float* __restrict__ S, const float* __restrict__ C,
    float* __restrict__ xl, float* __restrict__ xr, float* __restrict__ outp)
{
    __shared__ __align__(16) unsigned short hbh[64 * HS];
    __shared__ __align__(16) unsigned short hbl[64 * HS];
    __shared__ float smean[64], srho[64];
    const int tid = threadIdx.x;
    const int tile = blockIdx.x * 64;
    // ---- stage: load 64x64 fp32, row stats, convert to bf16 hi/lo in LDS ----
    {
        const int row = tid >> 2, q = tid & 3;
        const int node = min(tile + row, NN - 1);
        const float* hp = h + (size_t)node * DD + q * 16;
        float4 v[4];
        #pragma unroll
        for (int i = 0; i < 4; ++i) v[i] = *(const float4*)(hp + i * 4);
        if (LN) {
            float sum = 0.f, ssq = 0.f;
            #pragma unroll
            for (int i = 0; i < 4; ++i) {
                sum += v[i].x + v[i].y + v[i].z + v[i].w;
                ssq += v[i].x * v[i].x + v[i].y * v[i].y + v[i].z * v[i].z + v[i].w * v[i].w;
            }
            sum += __shfl_xor(sum, 1, 64); ssq += __shfl_xor(ssq, 1, 64);
            sum += __shfl_xor(sum, 2, 64); ssq += __shfl_xor(ssq, 2, 64);
            if (q == 0) {
                float mean = sum * 0.015625f;
                float var = ssq * 0.015625f - mean * mean;
                smean[row] = mean;
                srho[row] = rsqrtf(var + 1e-5f);
            }
        }
        #pragma unroll
        for (int half = 0; half < 2; ++half) {
            bf16x8 ph, pl;
            #pragma unroll
            for (int e = 0; e < 8; ++e) {
                float f = (&v[half * 2 + (e >> 2)].x)[e & 3];
                unsigned short hi = f2bf(f);
                unsigned short lo = f2bf(f - bf2f(hi));
                ph[e] = (short)hi; pl[e] = (short)lo;
            }
            const int so = row * HS + q * 16 + half * 8;
            *(bf16x8*)&hbh[so] = ph;
            *(bf16x8*)&hbl[so] = pl;
        }
    }
    __syncthreads();
    const int lane = tid & 63;
    const int wslot = tid >> 6;
    const int li16 = lane & 15;
    const int g16 = lane >> 4;
    const int NCT = CTW * 4;
    f32x4 acc[CTW][4];
    #pragma unroll
    for (int c = 0; c < CTW; ++c)
        #pragma unroll
        for (int rt = 0; rt < 4; ++rt) acc[c][rt] = (f32x4){0.f, 0.f, 0.f, 0.f};
    #pragma unroll
    for (int kk = 0; kk < 2; ++kk) {
        bf16x8 ah[4], al[4];
        #pragma unroll
        for (int rt = 0; rt < 4; ++rt) {
            const int so = (rt * 16 + li16) * HS + kk * 32 + g16 * 8;
            ah[rt] = *(const bf16x8*)&hbh[so];
            al[rt] = *(const bf16x8*)&hbl[so];
        }
        #pragma unroll
        for (int c = 0; c < CTW; ++c) {
            const int ct = wslot + c * 4;
            const unsigned short* bp = aT + (ct * 16 + li16) * 64 + kk * 32 + g16 * 8;
            bf16x8 bh = *(const bf16x8*)bp;
            bf16x8 bl = *(const bf16x8*)(bp + NCT * 16 * 64);
            #pragma unroll
            for (int rt = 0; rt < 4; ++rt) {
                acc[c][rt] = __builtin_amdgcn_mfma_f32_16x16x32_bf16(ah[rt], bh, acc[c][rt], 0, 0, 0);
                acc[c][rt] = __builtin_amdgcn_mfma_f32_16x16x32_bf16(al[rt], bh, acc[c][rt], 0, 0, 0);
                acc[c][rt] = __builtin_amdgcn_mfma_f32_16x16x32_bf16(ah[rt], bl, acc[c][rt], 0, 0, 0);
            }
        }
    }
    // ---- epilogue ----
    #pragma unroll
    for (int c = 0; c < CTW; ++c) {
        const int ct = wslot + c * 4;
        const int col = ct * 16 + li16;
        const float Cc = C[col];
        float Sc = 0.f;
        if (LN) Sc = S[col];
        float* xb;
        int cc;
        if (LN) { xb = (ct < 4) ? xl : xr; cc = col & 63; }
        else    { xb = outp; cc = col; }
        #pragma unroll
        for (int rt = 0; rt < 4; ++rt) {
            const int r0 = rt * 16 + g16 * 4;
            #pragma unroll
            for (int j = 0; j < 4; ++j) {
                const int row2 = r0 + j;
                const int node = tile + row2;
                if (node < NN) {
                    float p = acc[c][rt][j];
                    float val;
                    if (LN) val = fmaf(srho[row2], p - smean[row2] * Sc, Cc);
                    else    val = p + Cc;
                    xb[(size_t)node * DD + cc] = val;
                }
            }
        }
    }
}

// ---------------- aggregation: one wave per target node, 16 lanes x 4 edges ----------------
__global__ __launch_bounds__(256) void k_agg(
    const int* __restrict__ rowptr, const int* __restrict__ csr,
    const float* __restrict__ xl, const float* __restrict__ xr,
    const float* __restrict__ att, const float* __restrict__ cbias,
    const float* __restrict__ h_in, float* __restrict__ h_out)
{
    const int lane = threadIdx.x & 63;
    const int li   = lane & 15;     // feature-quad index
    const int sub  = lane >> 4;     // edge slot 0..3
    const int wid  = (blockIdx.x * 256 + threadIdx.x) >> 6;
    const int nw   = gridDim.x * 4;
    const float4 a4  = *(const float4*)&att[li * 4];
    const float4 cb4 = *(const float4*)&cbias[li * 4];
    for (int n = wid; n < NN; n += nw) {
        const float4 xrt = *(const float4*)&xr[(size_t)n * DD + li * 4];
        const int beg = rowptr[n], end = rowptr[n + 1];   // len >= 1 (self first)
        const int end1 = end - 1;
        int j  = beg + sub;
        int jc = min(j, end1);
        int s  = csr[jc];
        float4 v = *(const float4*)&xl[(size_t)s * DD + li * 4];
        float  den = 0.f;
        float4 acc = make_float4(0.f, 0.f, 0.f, 0.f);
        const int nch = (end - beg + 3) >> 2;
        for (int c = 0; c < nch; ++c) {
            float4 cur = v;
            const int jcur = j;
            j += 4;
            jc = min(j, end1);
            s  = csr[jc];
            v  = *(const float4*)&xl[(size_t)s * DD + li * 4];   // unconditional prefetch
            float p = leaky(cur.x + xrt.x) * a4.x;
            p = fmaf(leaky(cur.y + xrt.y), a4.y, p);
            p = fmaf(leaky(cur.z + xrt.z), a4.z, p);
            p = fmaf(leaky(cur.w + xrt.w), a4.w, p);
            p += __shfl_xor(p, 1, 64);
            p += __shfl_xor(p, 2, 64);
            p += __shfl_xor(p, 4, 64);
            p += __shfl_xor(p, 8, 64);
            float ex = (jcur < end) ? __expf(p) : 0.f;
            den += ex;
            acc.x = fmaf(ex, cur.x, acc.x);
            acc.y = fmaf(ex, cur.y, acc.y);
            acc.z = fmaf(ex, cur.z, acc.z);
            acc.w = fmaf(ex, cur.w, acc.w);
        }
        #pragma unroll
        for (int o = 16; o < 64; o <<= 1) {
            acc.x += __shfl_xor(acc.x, o, 64);
            acc.y += __shfl_xor(acc.y, o, 64);
            acc.z += __shfl_xor(acc.z, o, 64);
            acc.w += __shfl_xor(acc.w, o, 64);
            den   += __shfl_xor(den,   o, 64);
        }
        if (sub == 0) {
            const float id = 1.f / (den + 1e-16f);
            const float4 hi = *(const float4*)&h_in[(size_t)n * DD + li * 4];
            float4 o4;
            o4.x = gelu_exact(fmaf(acc.x, id, cb4.x)) + hi.x;
            o4.y = gelu_exact(fmaf(acc.y, id, cb4.y)) + hi.y;
            o4.z = gelu_exact(fmaf(acc.z, id, cb4.z)) + hi.z;
            o4.w = gelu_exact(fmaf(acc.w, id, cb4.w)) + hi.w;
            *(float4*)&h_out[(size_t)n * DD + li * 4] = o4;
        }
    }
}

extern "C" void kernel_launch(void* const* d_in, const int* in_sizes, int n_in,
                              void* d_out, int out_size, void* d_ws, size_t ws_size,
                              hipStream_t stream) {
    const int*   edge_index = (const int*)d_in[1];
    const int*   src   = edge_index;
    const int*   tgt   = edge_index + NE;
    const float* emb   = (const float*)d_in[2];
    const float* ln_g  = (const float*)d_in[3];
    const float* ln_b  = (const float*)d_in[4];
    const float* Wl    = (const float*)d_in[5];
    const float* Wr    = (const float*)d_in[6];
    const float* att   = (const float*)d_in[7];
    const float* cbias = (const float*)d_in[8];
    const float* pw    = (const float*)d_in[9];
    const float* pb    = (const float*)d_in[10];
    float* out = (float*)d_out;

    float* xl = (float*)d_ws;
    float* xr = xl + (size_t)NN * DD;
    int* csr             = (int*)(xr + (size_t)NN * DD);   // NE+NN
    unsigned int* ebuf   = (unsigned int*)(csr + NE + NN);
    int* rowptr          = (int*)(ebuf + NE);              // NN+8
    int* bcnt            = rowptr + NN + 8;                // 392 (padded)
    int* bbase           = bcnt + 392;                     // 400 (padded)
    int* wbase           = bbase + 400;                    // 400 (padded)
    unsigned short* aT0  = (unsigned short*)(wbase + 400); // 2*128*64
    unsigned short* aT1  = aT0 + 2 * 128 * 64;
    unsigned short* fT   = aT1 + 2 * 128 * 64;             // 2*64*64
    float* S0 = (float*)(fT + 2 * 64 * 64);
    float* C0 = S0 + 128;
    float* S1 = C0 + 128;
    float* C1 = S1 + 128;
    float* Cf = C1 + 128;

    const int AGG_BLOCKS = 2048;

    // ---- weight precompute (tiny) ----
    k_wprep<<<1, 128, 0, stream>>>(Wl, Wr, ln_g, ln_b, aT0, S0, C0);
    k_wprep<<<1, 128, 0, stream>>>(Wl + DD * DD, Wr + DD * DD, ln_g + DD, ln_b + DD, aT1, S1, C1);
    k_wfinal<<<1, 64, 0, stream>>>(pw, pb, fT, Cf);

    // ---- CSR build (two-level bucket sort by target, self-loops embedded) ----
    hipMemsetAsync(bcnt, 0, NB * sizeof(int), stream);
    k_bcount<<<256, 256, 0, stream>>>(tgt, bcnt);
    k_bscan<<<1, 512, 0, stream>>>(bcnt, bbase, wbase);
    k_bscatter<<<(NE + SCH - 1) / SCH, 256, 0, stream>>>(src, tgt, wbase, ebuf);
    k_bfinal<<<NB, 256, 0, stream>>>(bbase, ebuf, rowptr, csr);

    // ---- layer 0 ----
    k_gemm<2, true><<<GB, 256, 0, stream>>>(emb, aT0, S0, C0, xl, xr, nullptr);
    k_agg<<<AGG_BLOCKS, 256, 0, stream>>>(rowptr, csr, xl, xr, att, cbias, emb, out);        // h1

    // ---- layer 1 ----
    k_gemm<2, true><<<GB, 256, 0, stream>>>(out, aT1, S1, C1, xl, xr, nullptr);
    k_agg<<<AGG_BLOCKS, 256, 0, stream>>>(rowptr, csr, xl, xr, att + DD, cbias + DD, out, out); // h2

    // ---- final projection (MFMA, in-place per row tile) ----
    k_gemm<1, false><<<GB, 256, 0, stream>>>(out, fT, nullptr, Cf, nullptr, nullptr, out);
}